// Round 6
// baseline (205.888 us; speedup 1.0000x reference)
//
#include <hip/hip_runtime.h>
#include <hip/hip_bf16.h>

typedef __bf16 bf16_t;
typedef __bf16 bf16x4 __attribute__((ext_vector_type(4)));
typedef __bf16 bf16x8 __attribute__((ext_vector_type(8)));
typedef float f32x4 __attribute__((ext_vector_type(4)));

#define MFMA16(a, b, c) __builtin_amdgcn_mfma_f32_16x16x32_bf16(a, b, c, 0, 0, 0)

// B=4, T=4096, E=1024, H=64
static constexpr float LOG2E = 1.44269504088896340736f;
static constexpr float QSCALE = LOG2E / 32.0f;  // E^-0.5 * log2(e), folded into q

// ws layout (bytes):
//   qs  [16384][64] bf16 @ 0     (2 MB)   q * QSCALE
//   ks  [16384][64] bf16 @ 2 MB  (2 MB)
//   vt  [4][64][4096] bf16 @ 4 MB (2 MB)  v transposed per batch
//   wt  [3][64][1024] bf16 @ 6 MB (384 KB)
//   po  [1024][64][64] bf16 @ 8 MB (8 MB)  split-K partial O (4 splits)
//   pm  [1024][64] f32 @ 16 MB (256 KB)
//   pls [1024][64] f32 @ 16.25 MB (256 KB)

// ---- DPP 16-lane-row reduces ----
template <int CTRL>
__device__ __forceinline__ float dppf(float v) {
    return __builtin_bit_cast(
        float, __builtin_amdgcn_mov_dpp(__builtin_bit_cast(int, v), CTRL, 0xf, 0xf, true));
}
__device__ __forceinline__ float rmax16(float t) {
    t = fmaxf(t, dppf<0xB1>(t));
    t = fmaxf(t, dppf<0x4E>(t));
    t = fmaxf(t, dppf<0x141>(t));
    t = fmaxf(t, dppf<0x140>(t));
    return t;
}
__device__ __forceinline__ float rsum16(float t) {
    t += dppf<0xB1>(t);
    t += dppf<0x4E>(t);
    t += dppf<0x141>(t);
    t += dppf<0x140>(t);
    return t;
}

// 48 blocks x 256: LDS tile transpose, coalesced both sides.
__global__ __launch_bounds__(256) void transpose_w_kernel(const float* __restrict__ Wq,
                                                          const float* __restrict__ Wk,
                                                          const float* __restrict__ Wv,
                                                          bf16_t* __restrict__ wt) {
    __shared__ float tile[64][68];
    int w = blockIdx.x >> 4;
    int e0 = (blockIdx.x & 15) * 64;
    const float* W = (w == 0) ? Wq : ((w == 1) ? Wk : Wv);
    int t = threadIdx.x;
    int r = t >> 2, q = t & 3;
    const float* src = W + (size_t)(e0 + r) * 64 + q * 16;
#pragma unroll
    for (int jj = 0; jj < 4; ++jj) {
        float4 v = *(const float4*)(src + jj * 4);
        *(float4*)&tile[r][q * 16 + jj * 4] = v;
    }
    __syncthreads();
    bf16_t* dst = wt + (size_t)w * 65536 + (size_t)r * 1024 + e0 + q * 16;
    bf16x8 o0, o1;
#pragma unroll
    for (int jj = 0; jj < 8; ++jj) o0[jj] = (bf16_t)tile[q * 16 + jj][r];
#pragma unroll
    for (int jj = 0; jj < 8; ++jj) o1[jj] = (bf16_t)tile[q * 16 + 8 + jj][r];
    *(bf16x8*)dst = o0;
    *(bf16x8*)(dst + 8) = o1;
}

// 1024 blocks x 256 (4 waves). Block: 16 rows; wave: 3 col-chunks x K=1024.
// No x LDS stage: direct global loads (L2 reuse across waves) with explicit
// register double-buffer so loads for step k+1 fly during step k's MFMA.
__global__ __launch_bounds__(256) void proj_kernel(const float* __restrict__ x,
                                                   const bf16_t* __restrict__ wt,
                                                   bf16_t* __restrict__ qs,
                                                   bf16_t* __restrict__ ks,
                                                   bf16_t* __restrict__ vt) {
    __shared__ float vred[64][17];
    int t = threadIdx.x;
    int wave = t >> 6, lane = t & 63;
    int lr = lane & 15, lg = lane >> 4;
    int r0 = blockIdx.x * 16;
    int gc0 = wave * 3;

    const float* xp = x + (size_t)(r0 + lr) * 1024 + lg * 8;
    const bf16_t* wp0 = wt + ((gc0 + 0) >> 2) * 65536 + (((gc0 + 0) & 3) * 16 + lr) * 1024 + lg * 8;
    const bf16_t* wp1 = wt + ((gc0 + 1) >> 2) * 65536 + (((gc0 + 1) & 3) * 16 + lr) * 1024 + lg * 8;
    const bf16_t* wp2 = wt + ((gc0 + 2) >> 2) * 65536 + (((gc0 + 2) & 3) * 16 + lr) * 1024 + lg * 8;

    f32x4 a0 = {0.f, 0.f, 0.f, 0.f}, a1 = a0, a2 = a0;

    float4 xa = *(const float4*)(xp);
    float4 xb = *(const float4*)(xp + 4);
    bf16x8 b0 = *(const bf16x8*)(wp0);
    bf16x8 b1 = *(const bf16x8*)(wp1);
    bf16x8 b2 = *(const bf16x8*)(wp2);

#pragma unroll 4
    for (int kk = 0; kk < 32; ++kk) {
        int nk = (kk + 1) & 31;  // wrap: unconditional, always in-bounds
        float4 nxa = *(const float4*)(xp + nk * 32);
        float4 nxb = *(const float4*)(xp + nk * 32 + 4);
        bf16x8 nb0 = *(const bf16x8*)(wp0 + nk * 32);
        bf16x8 nb1 = *(const bf16x8*)(wp1 + nk * 32);
        bf16x8 nb2 = *(const bf16x8*)(wp2 + nk * 32);
        bf16x8 af;
        af[0] = (bf16_t)xa.x; af[1] = (bf16_t)xa.y; af[2] = (bf16_t)xa.z; af[3] = (bf16_t)xa.w;
        af[4] = (bf16_t)xb.x; af[5] = (bf16_t)xb.y; af[6] = (bf16_t)xb.z; af[7] = (bf16_t)xb.w;
        a0 = MFMA16(af, b0, a0);
        a1 = MFMA16(af, b1, a1);
        a2 = MFMA16(af, b2, a2);
        xa = nxa; xb = nxb; b0 = nb0; b1 = nb1; b2 = nb2;
    }

    f32x4 accs[3] = {a0, a1, a2};
#pragma unroll
    for (int c = 0; c < 3; ++c) {
        int gc = gc0 + c;
        int w3 = gc >> 2;
        int h = (gc & 3) * 16 + lr;
#pragma unroll
        for (int r = 0; r < 4; ++r) {
            int rr = r0 + lg * 4 + r;
            float v = accs[c][r];
            if (w3 == 0) {
                qs[(size_t)rr * 64 + h] = (bf16_t)(v * QSCALE);
            } else if (w3 == 1) {
                ks[(size_t)rr * 64 + h] = (bf16_t)v;
            } else {
                vred[(gc - 8) * 16 + lr][lg * 4 + r] = v;  // [v-col][t-local]
            }
        }
    }
    __syncthreads();
    // cooperative vt store: thread -> (h = t>>2, 4 t-values)
    {
        int h = t >> 2, j4 = (t & 3) * 4;
        int bb = r0 >> 12, t0 = r0 & 4095;
        bf16x4 v4;
#pragma unroll
        for (int jj = 0; jj < 4; ++jj) v4[jj] = (bf16_t)vred[h][j4 + jj];
        *(bf16x4*)(vt + ((size_t)(bb * 64 + h)) * 4096 + t0 + j4) = v4;
    }
}

// 1024 blocks x 256 (4 waves): {b:4} x {qt:64 of QBLK=64 rows} x {split:4}.
// Wave w owns rows q0+16w..+16. K/V tiles (64 keys) cooperatively staged in
// LDS, double-buffered, reg-prefetch before compute.
__global__ __launch_bounds__(256) void attn_kernel(const bf16_t* __restrict__ qs,
                                                   const bf16_t* __restrict__ ks,
                                                   const bf16_t* __restrict__ vt,
                                                   bf16_t* __restrict__ po,
                                                   float* __restrict__ pm,
                                                   float* __restrict__ pls) {
    __shared__ __align__(16) bf16_t kt[2][64 * 64];
    __shared__ __align__(16) bf16_t vtl[2][64 * 64];
    __shared__ __align__(16) bf16_t pl[4][16][80];

    int tid = threadIdx.x;
    int wave = tid >> 6, lane = tid & 63;
    int lr = lane & 15, lg = lane >> 4;

    int bid = blockIdx.x;
    int s = bid & 3;
    int jq = (bid >> 2) & 63;
    int b = bid >> 8;
    int qt = (jq & 1) ? (63 - (jq >> 1)) : (jq >> 1);  // triangle balance
    int q0 = qt << 6;
    int nk = qt + 1;                    // 64-key tiles up to diagonal
    int lo = (nk * s) >> 2;
    int hi = (nk * (s + 1)) >> 2;
    int ntile = hi - lo;

    // staging: thread covers slots (srow, sc) and (srow+32, sc); both-sides swizzle
    int srow = tid >> 3, sc = tid & 7;
    int sw8 = srow & 7;  // (srow+32)&7 == srow&7
    int koff0 = srow * 64 + ((sc ^ sw8) * 8);
    int koff1 = (32 + srow) * 64 + ((sc ^ sw8) * 8);
    const bf16_t* kg = ks + ((size_t)b * 4096) * 64;
    const bf16_t* vg = vt + ((size_t)b * 64) * 4096;

    const bf16_t* qb = qs + (size_t)(b * 4096 + q0 + wave * 16 + lr) * 64 + lg * 8;
    bf16x8 qf0 = *(const bf16x8*)qb;
    bf16x8 qf1 = *(const bf16x8*)(qb + 32);

    f32x4 o[4];
    float m[4], l[4];
#pragma unroll
    for (int r = 0; r < 4; ++r) {
        o[r] = (f32x4){0.f, 0.f, 0.f, 0.f};
        m[r] = -INFINITY;
        l[r] = 0.f;
    }

    bf16x8 kr0, kr1, vr0, vr1;
    if (ntile > 0) {
        int kb = lo << 6;
        kr0 = *(const bf16x8*)(kg + (size_t)(kb + srow) * 64 + sc * 8);
        kr1 = *(const bf16x8*)(kg + (size_t)(kb + 32 + srow) * 64 + sc * 8);
        vr0 = *(const bf16x8*)(vg + (size_t)srow * 4096 + kb + sc * 8);
        vr1 = *(const bf16x8*)(vg + (size_t)(32 + srow) * 4096 + kb + sc * 8);
    }

    for (int ti = 0; ti < ntile; ++ti) {
        int cur = ti & 1;
        *(bf16x8*)(&kt[cur][koff0]) = kr0;
        *(bf16x8*)(&kt[cur][koff1]) = kr1;
        *(bf16x8*)(&vtl[cur][koff0]) = vr0;
        *(bf16x8*)(&vtl[cur][koff1]) = vr1;
        __syncthreads();
        if (ti + 1 < ntile) {  // prefetch next tile; in flight during compute
            int kb = (lo + ti + 1) << 6;
            kr0 = *(const bf16x8*)(kg + (size_t)(kb + srow) * 64 + sc * 8);
            kr1 = *(const bf16x8*)(kg + (size_t)(kb + 32 + srow) * 64 + sc * 8);
            vr0 = *(const bf16x8*)(vg + (size_t)srow * 4096 + kb + sc * 8);
            vr1 = *(const bf16x8*)(vg + (size_t)(32 + srow) * 4096 + kb + sc * 8);
        }

        int gt = lo + ti;
        int kb = gt << 6;
        const bf16_t* kbuf = kt[cur];
        const bf16_t* vbuf = vtl[cur];

        f32x4 z = {0.f, 0.f, 0.f, 0.f};
        f32x4 sv[4];
#pragma unroll
        for (int g = 0; g < 4; ++g) {
            int krow = g * 16 + lr;
            int sw = krow & 7;
            bf16x8 kf0 = *(const bf16x8*)(kbuf + krow * 64 + ((lg ^ sw) * 8));
            bf16x8 kf1 = *(const bf16x8*)(kbuf + krow * 64 + (((4 | lg) ^ sw) * 8));
            sv[g] = MFMA16(qf0, kf0, z);
            sv[g] = MFMA16(qf1, kf1, sv[g]);
        }

        if (gt == nk - 1) {  // diagonal tile
#pragma unroll
            for (int r = 0; r < 4; ++r) {
                int qrow = q0 + wave * 16 + lg * 4 + r;
#pragma unroll
                for (int g = 0; g < 4; ++g)
                    if (kb + g * 16 + lr > qrow) sv[g][r] = -INFINITY;
            }
        }

#pragma unroll
        for (int r = 0; r < 4; ++r) {
            float t2 = fmaxf(fmaxf(sv[0][r], sv[1][r]), fmaxf(sv[2][r], sv[3][r]));
            t2 = rmax16(t2);
            float mn = fmaxf(m[r], t2);
            float a = __builtin_amdgcn_exp2f(m[r] - mn);
            float p0 = __builtin_amdgcn_exp2f(sv[0][r] - mn);
            float p1 = __builtin_amdgcn_exp2f(sv[1][r] - mn);
            float p2 = __builtin_amdgcn_exp2f(sv[2][r] - mn);
            float p3 = __builtin_amdgcn_exp2f(sv[3][r] - mn);
            float rs = rsum16((p0 + p1) + (p2 + p3));
            l[r] = l[r] * a + rs;
            m[r] = mn;
            o[0][r] *= a; o[1][r] *= a; o[2][r] *= a; o[3][r] *= a;
            int prow = lg * 4 + r;
            pl[wave][prow][lr] = (bf16_t)p0;
            pl[wave][prow][16 + lr] = (bf16_t)p1;
            pl[wave][prow][32 + lr] = (bf16_t)p2;
            pl[wave][prow][48 + lr] = (bf16_t)p3;
        }

        bf16x8 pa0 = *(const bf16x8*)&pl[wave][lr][lg * 8];
        bf16x8 pa1 = *(const bf16x8*)&pl[wave][lr][32 + lg * 8];
#pragma unroll
        for (int oc = 0; oc < 4; ++oc) {
            int drow = oc * 16 + lr;
            int sw = drow & 7;
            bf16x8 vf0 = *(const bf16x8*)(vbuf + drow * 64 + ((lg ^ sw) * 8));
            bf16x8 vf1 = *(const bf16x8*)(vbuf + drow * 64 + (((4 | lg) ^ sw) * 8));
            o[oc] = MFMA16(pa0, vf0, o[oc]);
            o[oc] = MFMA16(pa1, vf1, o[oc]);
        }
    }

    // partial outputs (unnormalized o, m, l)
    size_t pblk = ((size_t)((b << 6) + qt) << 2) + s;
    bf16_t* pop = po + pblk * 4096;
#pragma unroll
    for (int r = 0; r < 4; ++r) {
        int row = wave * 16 + lg * 4 + r;
#pragma unroll
        for (int oc = 0; oc < 4; ++oc) pop[row * 64 + oc * 16 + lr] = (bf16_t)o[oc][r];
        if (lr == r) {
            pm[pblk * 64 + row] = m[r];
            pls[pblk * 64 + row] = l[r];
        }
    }
}

// 256 blocks x 256: merge the 4 key-splits per row, normalize, write f32 out.
__global__ __launch_bounds__(256) void merge_kernel(const bf16_t* __restrict__ po,
                                                    const float* __restrict__ pm,
                                                    const float* __restrict__ pls,
                                                    float* __restrict__ out) {
    int gid = blockIdx.x * 256 + threadIdx.x;  // 65536 = 16384 rows x 4 col-chunks
    int row = gid >> 2, cq = gid & 3;
    int b = row >> 12, t = row & 4095;
    int qt = t >> 6, lrow = t & 63;
    int pb = ((b << 6) + qt) << 2;

    float mm[4], w[4];
    float M = -INFINITY;
#pragma unroll
    for (int i = 0; i < 4; ++i) {
        mm[i] = pm[(size_t)(pb + i) * 64 + lrow];
        M = fmaxf(M, mm[i]);
    }
    float L = 0.f;
#pragma unroll
    for (int i = 0; i < 4; ++i) {
        w[i] = (mm[i] == -INFINITY) ? 0.f : __builtin_amdgcn_exp2f(mm[i] - M);
        L += pls[(size_t)(pb + i) * 64 + lrow] * w[i];
    }
    float rL = 1.0f / L;

    float acc[16];
#pragma unroll
    for (int j = 0; j < 16; ++j) acc[j] = 0.f;
#pragma unroll
    for (int i = 0; i < 4; ++i) {
        const bf16_t* p = po + ((size_t)(pb + i) * 64 + lrow) * 64 + cq * 16;
        bf16x8 x0 = *(const bf16x8*)p, x1 = *(const bf16x8*)(p + 8);
#pragma unroll
        for (int j = 0; j < 8; ++j) acc[j] += w[i] * (float)x0[j];
#pragma unroll
        for (int j = 0; j < 8; ++j) acc[8 + j] += w[i] * (float)x1[j];
    }
    float* op = out + (size_t)row * 64 + cq * 16;
#pragma unroll
    for (int j = 0; j < 16; ++j) op[j] = acc[j] * rL;
}

extern "C" void kernel_launch(void* const* d_in, const int* in_sizes, int n_in,
                              void* d_out, int out_size, void* d_ws, size_t ws_size,
                              hipStream_t stream) {
    const float* x  = (const float*)d_in[0];
    const float* Wq = (const float*)d_in[1];
    const float* Wk = (const float*)d_in[2];
    const float* Wv = (const float*)d_in[3];
    float* out = (float*)d_out;

    char* ws = (char*)d_ws;
    bf16_t* qs = (bf16_t*)(ws);
    bf16_t* ks = (bf16_t*)(ws + (2u << 20));
    bf16_t* vt = (bf16_t*)(ws + (4u << 20));
    bf16_t* wt = (bf16_t*)(ws + (6u << 20));
    bf16_t* po = (bf16_t*)(ws + (8u << 20));
    float*  pm = (float*)(ws + (16u << 20));
    float*  pls = (float*)(ws + (16u << 20) + (256u << 10));

    transpose_w_kernel<<<48, 256, 0, stream>>>(Wq, Wk, Wv, wt);
    proj_kernel<<<1024, 256, 0, stream>>>(x, wt, qs, ks, vt);
    attn_kernel<<<1024, 256, 0, stream>>>(qs, ks, vt, po, pm, pls);
    merge_kernel<<<256, 256, 0, stream>>>(po, pm, pls, out);
}

// Round 7
// 174.428 us; speedup vs baseline: 1.1804x; 1.1804x over previous
//
#include <hip/hip_runtime.h>
#include <hip/hip_bf16.h>

typedef __bf16 bf16_t;
typedef __bf16 bf16x4 __attribute__((ext_vector_type(4)));
typedef __bf16 bf16x8 __attribute__((ext_vector_type(8)));
typedef float f32x4 __attribute__((ext_vector_type(4)));

#define MFMA16(a, b, c) __builtin_amdgcn_mfma_f32_16x16x32_bf16(a, b, c, 0, 0, 0)

// B=4, T=4096, E=1024, H=64
static constexpr float LOG2E = 1.44269504088896340736f;
static constexpr float QSCALE = LOG2E / 32.0f;  // E^-0.5 * log2(e), folded into q

// ws layout (bytes):
//   qs  [16384][64] bf16 @ 0     (2 MB)   q * QSCALE
//   ks  [16384][64] bf16 @ 2 MB  (2 MB)
//   vt  [4][64][4096] bf16 @ 4 MB (2 MB)  v transposed per batch
//   wt  [192][1024] bf16 @ 6 MB (384 KB)  (= [3][64][1024])
//   po  [1024][64][64] bf16 @ 8 MB (8 MB)
//   pm  [1024][64] f32 @ 16 MB (256 KB)
//   pls [1024][64] f32 @ 16.25 MB (256 KB)

__device__ __forceinline__ void gload_lds16(const bf16_t* src, bf16_t* dst) {
    __builtin_amdgcn_global_load_lds(
        (const __attribute__((address_space(1))) void*)src,
        (__attribute__((address_space(3))) void*)dst, 16, 0, 0);
}

// ---- DPP 16-lane-row reduces ----
template <int CTRL>
__device__ __forceinline__ float dppf(float v) {
    return __builtin_bit_cast(
        float, __builtin_amdgcn_mov_dpp(__builtin_bit_cast(int, v), CTRL, 0xf, 0xf, true));
}
__device__ __forceinline__ float rmax16(float t) {
    t = fmaxf(t, dppf<0xB1>(t));
    t = fmaxf(t, dppf<0x4E>(t));
    t = fmaxf(t, dppf<0x141>(t));
    t = fmaxf(t, dppf<0x140>(t));
    return t;
}
__device__ __forceinline__ float rsum16(float t) {
    t += dppf<0xB1>(t);
    t += dppf<0x4E>(t);
    t += dppf<0x141>(t);
    t += dppf<0x140>(t);
    return t;
}

// 48 blocks x 256: LDS tile transpose, coalesced both sides.
__global__ __launch_bounds__(256) void transpose_w_kernel(const float* __restrict__ Wq,
                                                          const float* __restrict__ Wk,
                                                          const float* __restrict__ Wv,
                                                          bf16_t* __restrict__ wt) {
    __shared__ float tile[64][68];
    int w = blockIdx.x >> 4;
    int e0 = (blockIdx.x & 15) * 64;
    const float* W = (w == 0) ? Wq : ((w == 1) ? Wk : Wv);
    int t = threadIdx.x;
    int r = t >> 2, q = t & 3;
    const float* src = W + (size_t)(e0 + r) * 64 + q * 16;
#pragma unroll
    for (int jj = 0; jj < 4; ++jj) {
        float4 v = *(const float4*)(src + jj * 4);
        *(float4*)&tile[r][q * 16 + jj * 4] = v;
    }
    __syncthreads();
    bf16_t* dst = wt + (size_t)w * 65536 + (size_t)r * 1024 + e0 + q * 16;
    bf16x8 o0, o1;
#pragma unroll
    for (int jj = 0; jj < 8; ++jj) o0[jj] = (bf16_t)tile[q * 16 + jj][r];
#pragma unroll
    for (int jj = 0; jj < 8; ++jj) o1[jj] = (bf16_t)tile[q * 16 + 8 + jj][r];
    *(bf16x8*)dst = o0;
    *(bf16x8*)(dst + 8) = o1;
}

// 1024 blocks x 256 (4 waves). Block: 32 rows x 96 cols (col-half = bid&1).
// K-chunks of 128, LDS double-buffered: wt via global_load_lds (pre-swizzled
// source, linear dest), x reg-staged f32->bf16 with issue-early/write-late.
// Swizzle: 16B-unit index e' = e ^ (row_or_col & 15) -> <=2-way bank conflict.
__global__ __launch_bounds__(256) void proj_kernel(const float* __restrict__ x,
                                                   const bf16_t* __restrict__ wt,
                                                   bf16_t* __restrict__ qs,
                                                   bf16_t* __restrict__ ks,
                                                   bf16_t* __restrict__ vt) {
    __shared__ __align__(16) bf16_t xa[2][32 * 128];
    __shared__ __align__(16) bf16_t wb[2][96 * 128];
    __shared__ float vred[64][33];

    int tid = threadIdx.x;
    int wave = tid >> 6, lane = tid & 63;
    int lr = lane & 15, lg = lane >> 4;
    int wr = wave >> 1, wc = wave & 1;
    int bid = blockIdx.x;
    int h2 = bid & 1;
    int r0 = (bid >> 1) << 5;

    const bf16_t* wtb = wt + (size_t)h2 * 96 * 1024;

    // x staging units for this thread (u0 = tid, u1 = tid+256)
    int xrow0 = tid >> 4, xe0 = tid & 15;
    int xrow1 = (tid + 256) >> 4, xe1 = tid & 15;  // (tid+256)&15 == tid&15
    const float* xs0 = x + (size_t)(r0 + xrow0) * 1024 + ((xe0 ^ (xrow0 & 15)) * 8);
    const float* xs1 = x + (size_t)(r0 + xrow1) * 1024 + ((xe1 ^ (xrow1 & 15)) * 8);
    int wubase = tid & ~63;  // wave-uniform unit base for gl_lds

    f32x4 a0 = {0.f, 0.f, 0.f, 0.f}, a1 = a0, a2 = a0;

    // ---- prologue: stage chunk 0 ----
#pragma unroll
    for (int call = 0; call < 6; ++call) {
        int u = call * 256 + tid;
        int col = u >> 4, ep = u & 15;
        gload_lds16(wtb + (size_t)col * 1024 + ((ep ^ (col & 15)) * 8),
                    &wb[0][(size_t)(call * 256 + wubase) * 8]);
    }
    {
        float4 p00 = *(const float4*)(xs0);
        float4 p01 = *(const float4*)(xs0 + 4);
        float4 p10 = *(const float4*)(xs1);
        float4 p11 = *(const float4*)(xs1 + 4);
        bf16x8 w0, w1;
        w0[0] = (bf16_t)p00.x; w0[1] = (bf16_t)p00.y; w0[2] = (bf16_t)p00.z; w0[3] = (bf16_t)p00.w;
        w0[4] = (bf16_t)p01.x; w0[5] = (bf16_t)p01.y; w0[6] = (bf16_t)p01.z; w0[7] = (bf16_t)p01.w;
        w1[0] = (bf16_t)p10.x; w1[1] = (bf16_t)p10.y; w1[2] = (bf16_t)p10.z; w1[3] = (bf16_t)p10.w;
        w1[4] = (bf16_t)p11.x; w1[5] = (bf16_t)p11.y; w1[6] = (bf16_t)p11.z; w1[7] = (bf16_t)p11.w;
        *(bf16x8*)&xa[0][(size_t)tid * 8] = w0;
        *(bf16x8*)&xa[0][(size_t)(tid + 256) * 8] = w1;
    }
    __syncthreads();

    for (int c = 0; c < 8; ++c) {
        int cur = c & 1;
        float4 p00, p01, p10, p11;
        if (c < 7) {
            int k0 = (c + 1) * 128;
            // issue async wt staging for next chunk (in flight during compute)
#pragma unroll
            for (int call = 0; call < 6; ++call) {
                int u = call * 256 + tid;
                int col = u >> 4, ep = u & 15;
                gload_lds16(wtb + (size_t)col * 1024 + k0 + ((ep ^ (col & 15)) * 8),
                            &wb[cur ^ 1][(size_t)(call * 256 + wubase) * 8]);
            }
            // issue x loads now; cvt+write after compute (T14)
            p00 = *(const float4*)(xs0 + k0);
            p01 = *(const float4*)(xs0 + k0 + 4);
            p10 = *(const float4*)(xs1 + k0);
            p11 = *(const float4*)(xs1 + k0 + 4);
        }

        // compute chunk c
#pragma unroll
        for (int sub = 0; sub < 4; ++sub) {
            int eu = sub * 4 + lg;
            bf16x8 af = *(const bf16x8*)&xa[cur][(size_t)((wr * 16 + lr) * 16 + (eu ^ lr)) * 8];
            bf16x8 b0 = *(const bf16x8*)&wb[cur][(size_t)((wc * 48 + lr) * 16 + (eu ^ lr)) * 8];
            bf16x8 b1 = *(const bf16x8*)&wb[cur][(size_t)((wc * 48 + 16 + lr) * 16 + (eu ^ lr)) * 8];
            bf16x8 b2 = *(const bf16x8*)&wb[cur][(size_t)((wc * 48 + 32 + lr) * 16 + (eu ^ lr)) * 8];
            a0 = MFMA16(af, b0, a0);
            a1 = MFMA16(af, b1, a1);
            a2 = MFMA16(af, b2, a2);
        }

        if (c < 7) {
            bf16x8 w0, w1;
            w0[0] = (bf16_t)p00.x; w0[1] = (bf16_t)p00.y; w0[2] = (bf16_t)p00.z; w0[3] = (bf16_t)p00.w;
            w0[4] = (bf16_t)p01.x; w0[5] = (bf16_t)p01.y; w0[6] = (bf16_t)p01.z; w0[7] = (bf16_t)p01.w;
            w1[0] = (bf16_t)p10.x; w1[1] = (bf16_t)p10.y; w1[2] = (bf16_t)p10.z; w1[3] = (bf16_t)p10.w;
            w1[4] = (bf16_t)p11.x; w1[5] = (bf16_t)p11.y; w1[6] = (bf16_t)p11.z; w1[7] = (bf16_t)p11.w;
            *(bf16x8*)&xa[cur ^ 1][(size_t)tid * 8] = w0;
            *(bf16x8*)&xa[cur ^ 1][(size_t)(tid + 256) * 8] = w1;
        }
        __syncthreads();
    }

    // ---- epilogue: store q/k direct, v via LDS transpose ----
    f32x4 accs[3] = {a0, a1, a2};
#pragma unroll
    for (int cc = 0; cc < 3; ++cc) {
        int gcol = h2 * 96 + wc * 48 + cc * 16 + lr;
        int w3 = gcol >> 6, h = gcol & 63;
#pragma unroll
        for (int r = 0; r < 4; ++r) {
            int lrow = wr * 16 + lg * 4 + r;
            int row = r0 + lrow;
            float v = accs[cc][r];
            if (w3 == 0) {
                qs[(size_t)row * 64 + h] = (bf16_t)(v * QSCALE);
            } else if (w3 == 1) {
                ks[(size_t)row * 64 + h] = (bf16_t)v;
            } else {
                vred[h][lrow] = v;
            }
        }
    }
    if (h2 == 1) {
        __syncthreads();
        int h = tid >> 2, j8 = (tid & 3) * 8;
        int bb = r0 >> 12, t0 = r0 & 4095;
        bf16x8 v8;
#pragma unroll
        for (int jj = 0; jj < 8; ++jj) v8[jj] = (bf16_t)vred[h][j8 + jj];
        *(bf16x8*)(vt + ((size_t)(bb * 64 + h)) * 4096 + t0 + j8) = v8;
    }
}

// 1024 blocks x 256 (4 waves): {b:4} x {qt:64 of QBLK=64 rows} x {split:4}.
// Wave w owns rows q0+16w..+16. K/V tiles (64 keys) cooperatively staged in
// LDS, double-buffered, reg-prefetch before compute.
__global__ __launch_bounds__(256) void attn_kernel(const bf16_t* __restrict__ qs,
                                                   const bf16_t* __restrict__ ks,
                                                   const bf16_t* __restrict__ vt,
                                                   bf16_t* __restrict__ po,
                                                   float* __restrict__ pm,
                                                   float* __restrict__ pls) {
    __shared__ __align__(16) bf16_t kt[2][64 * 64];
    __shared__ __align__(16) bf16_t vtl[2][64 * 64];
    __shared__ __align__(16) bf16_t pl[4][16][80];

    int tid = threadIdx.x;
    int wave = tid >> 6, lane = tid & 63;
    int lr = lane & 15, lg = lane >> 4;

    int bid = blockIdx.x;
    int s = bid & 3;
    int jq = (bid >> 2) & 63;
    int b = bid >> 8;
    int qt = (jq & 1) ? (63 - (jq >> 1)) : (jq >> 1);  // triangle balance
    int q0 = qt << 6;
    int nk = qt + 1;
    int lo = (nk * s) >> 2;
    int hi = (nk * (s + 1)) >> 2;
    int ntile = hi - lo;

    int srow = tid >> 3, sc = tid & 7;
    int sw8 = srow & 7;
    int koff0 = srow * 64 + ((sc ^ sw8) * 8);
    int koff1 = (32 + srow) * 64 + ((sc ^ sw8) * 8);
    const bf16_t* kg = ks + ((size_t)b * 4096) * 64;
    const bf16_t* vg = vt + ((size_t)b * 64) * 4096;

    const bf16_t* qb = qs + (size_t)(b * 4096 + q0 + wave * 16 + lr) * 64 + lg * 8;
    bf16x8 qf0 = *(const bf16x8*)qb;
    bf16x8 qf1 = *(const bf16x8*)(qb + 32);

    f32x4 o[4];
    float m[4], l[4];
#pragma unroll
    for (int r = 0; r < 4; ++r) {
        o[r] = (f32x4){0.f, 0.f, 0.f, 0.f};
        m[r] = -INFINITY;
        l[r] = 0.f;
    }

    bf16x8 kr0, kr1, vr0, vr1;
    if (ntile > 0) {
        int kb = lo << 6;
        kr0 = *(const bf16x8*)(kg + (size_t)(kb + srow) * 64 + sc * 8);
        kr1 = *(const bf16x8*)(kg + (size_t)(kb + 32 + srow) * 64 + sc * 8);
        vr0 = *(const bf16x8*)(vg + (size_t)srow * 4096 + kb + sc * 8);
        vr1 = *(const bf16x8*)(vg + (size_t)(32 + srow) * 4096 + kb + sc * 8);
    }

    for (int ti = 0; ti < ntile; ++ti) {
        int cur = ti & 1;
        *(bf16x8*)(&kt[cur][koff0]) = kr0;
        *(bf16x8*)(&kt[cur][koff1]) = kr1;
        *(bf16x8*)(&vtl[cur][koff0]) = vr0;
        *(bf16x8*)(&vtl[cur][koff1]) = vr1;
        __syncthreads();
        if (ti + 1 < ntile) {
            int kb = (lo + ti + 1) << 6;
            kr0 = *(const bf16x8*)(kg + (size_t)(kb + srow) * 64 + sc * 8);
            kr1 = *(const bf16x8*)(kg + (size_t)(kb + 32 + srow) * 64 + sc * 8);
            vr0 = *(const bf16x8*)(vg + (size_t)srow * 4096 + kb + sc * 8);
            vr1 = *(const bf16x8*)(vg + (size_t)(32 + srow) * 4096 + kb + sc * 8);
        }

        int gt = lo + ti;
        int kb = gt << 6;
        const bf16_t* kbuf = kt[cur];
        const bf16_t* vbuf = vtl[cur];

        f32x4 z = {0.f, 0.f, 0.f, 0.f};
        f32x4 sv[4];
#pragma unroll
        for (int g = 0; g < 4; ++g) {
            int krow = g * 16 + lr;
            int sw = krow & 7;
            bf16x8 kf0 = *(const bf16x8*)(kbuf + krow * 64 + ((lg ^ sw) * 8));
            bf16x8 kf1 = *(const bf16x8*)(kbuf + krow * 64 + (((4 | lg) ^ sw) * 8));
            sv[g] = MFMA16(qf0, kf0, z);
            sv[g] = MFMA16(qf1, kf1, sv[g]);
        }

        if (gt == nk - 1) {
#pragma unroll
            for (int r = 0; r < 4; ++r) {
                int qrow = q0 + wave * 16 + lg * 4 + r;
#pragma unroll
                for (int g = 0; g < 4; ++g)
                    if (kb + g * 16 + lr > qrow) sv[g][r] = -INFINITY;
            }
        }

#pragma unroll
        for (int r = 0; r < 4; ++r) {
            float t2 = fmaxf(fmaxf(sv[0][r], sv[1][r]), fmaxf(sv[2][r], sv[3][r]));
            t2 = rmax16(t2);
            float mn = fmaxf(m[r], t2);
            float a = __builtin_amdgcn_exp2f(m[r] - mn);
            float p0 = __builtin_amdgcn_exp2f(sv[0][r] - mn);
            float p1 = __builtin_amdgcn_exp2f(sv[1][r] - mn);
            float p2 = __builtin_amdgcn_exp2f(sv[2][r] - mn);
            float p3 = __builtin_amdgcn_exp2f(sv[3][r] - mn);
            float rs = rsum16((p0 + p1) + (p2 + p3));
            l[r] = l[r] * a + rs;
            m[r] = mn;
            o[0][r] *= a; o[1][r] *= a; o[2][r] *= a; o[3][r] *= a;
            int prow = lg * 4 + r;
            pl[wave][prow][lr] = (bf16_t)p0;
            pl[wave][prow][16 + lr] = (bf16_t)p1;
            pl[wave][prow][32 + lr] = (bf16_t)p2;
            pl[wave][prow][48 + lr] = (bf16_t)p3;
        }

        bf16x8 pa0 = *(const bf16x8*)&pl[wave][lr][lg * 8];
        bf16x8 pa1 = *(const bf16x8*)&pl[wave][lr][32 + lg * 8];
#pragma unroll
        for (int oc = 0; oc < 4; ++oc) {
            int drow = oc * 16 + lr;
            int sw = drow & 7;
            bf16x8 vf0 = *(const bf16x8*)(vbuf + drow * 64 + ((lg ^ sw) * 8));
            bf16x8 vf1 = *(const bf16x8*)(vbuf + drow * 64 + (((4 | lg) ^ sw) * 8));
            o[oc] = MFMA16(pa0, vf0, o[oc]);
            o[oc] = MFMA16(pa1, vf1, o[oc]);
        }
    }

    size_t pblk = ((size_t)((b << 6) + qt) << 2) + s;
    bf16_t* pop = po + pblk * 4096;
#pragma unroll
    for (int r = 0; r < 4; ++r) {
        int row = wave * 16 + lg * 4 + r;
#pragma unroll
        for (int oc = 0; oc < 4; ++oc) pop[row * 64 + oc * 16 + lr] = (bf16_t)o[oc][r];
        if (lr == r) {
            pm[pblk * 64 + row] = m[r];
            pls[pblk * 64 + row] = l[r];
        }
    }
}

// 256 blocks x 256: merge the 4 key-splits per row, normalize, write f32 out.
__global__ __launch_bounds__(256) void merge_kernel(const bf16_t* __restrict__ po,
                                                    const float* __restrict__ pm,
                                                    const float* __restrict__ pls,
                                                    float* __restrict__ out) {
    int gid = blockIdx.x * 256 + threadIdx.x;
    int row = gid >> 2, cq = gid & 3;
    int b = row >> 12, t = row & 4095;
    int qt = t >> 6, lrow = t & 63;
    int pb = ((b << 6) + qt) << 2;

    float mm[4], w[4];
    float M = -INFINITY;
#pragma unroll
    for (int i = 0; i < 4; ++i) {
        mm[i] = pm[(size_t)(pb + i) * 64 + lrow];
        M = fmaxf(M, mm[i]);
    }
    float L = 0.f;
#pragma unroll
    for (int i = 0; i < 4; ++i) {
        w[i] = (mm[i] == -INFINITY) ? 0.f : __builtin_amdgcn_exp2f(mm[i] - M);
        L += pls[(size_t)(pb + i) * 64 + lrow] * w[i];
    }
    float rL = 1.0f / L;

    float acc[16];
#pragma unroll
    for (int j = 0; j < 16; ++j) acc[j] = 0.f;
#pragma unroll
    for (int i = 0; i < 4; ++i) {
        const bf16_t* p = po + ((size_t)(pb + i) * 64 + lrow) * 64 + cq * 16;
        bf16x8 x0 = *(const bf16x8*)p, x1 = *(const bf16x8*)(p + 8);
#pragma unroll
        for (int j = 0; j < 8; ++j) acc[j] += w[i] * (float)x0[j];
#pragma unroll
        for (int j = 0; j < 8; ++j) acc[8 + j] += w[i] * (float)x1[j];
    }
    float* op = out + (size_t)row * 64 + cq * 16;
#pragma unroll
    for (int j = 0; j < 16; ++j) op[j] = acc[j] * rL;
}

extern "C" void kernel_launch(void* const* d_in, const int* in_sizes, int n_in,
                              void* d_out, int out_size, void* d_ws, size_t ws_size,
                              hipStream_t stream) {
    const float* x  = (const float*)d_in[0];
    const float* Wq = (const float*)d_in[1];
    const float* Wk = (const float*)d_in[2];
    const float* Wv = (const float*)d_in[3];
    float* out = (float*)d_out;

    char* ws = (char*)d_ws;
    bf16_t* qs = (bf16_t*)(ws);
    bf16_t* ks = (bf16_t*)(ws + (2u << 20));
    bf16_t* vt = (bf16_t*)(ws + (4u << 20));
    bf16_t* wt = (bf16_t*)(ws + (6u << 20));
    bf16_t* po = (bf16_t*)(ws + (8u << 20));
    float*  pm = (float*)(ws + (16u << 20));
    float*  pls = (float*)(ws + (16u << 20) + (256u << 10));

    transpose_w_kernel<<<48, 256, 0, stream>>>(Wq, Wk, Wv, wt);
    proj_kernel<<<1024, 256, 0, stream>>>(x, wt, qs, ks, vt);
    attn_kernel<<<1024, 256, 0, stream>>>(qs, ks, vt, po, pm, pls);
    merge_kernel<<<256, 256, 0, stream>>>(po, pm, pls, out);
}

// Round 8
// 163.762 us; speedup vs baseline: 1.2572x; 1.0651x over previous
//
#include <hip/hip_runtime.h>
#include <hip/hip_bf16.h>

typedef __bf16 bf16_t;
typedef __bf16 bf16x4 __attribute__((ext_vector_type(4)));
typedef __bf16 bf16x8 __attribute__((ext_vector_type(8)));
typedef float f32x4 __attribute__((ext_vector_type(4)));

#define MFMA16(a, b, c) __builtin_amdgcn_mfma_f32_16x16x32_bf16(a, b, c, 0, 0, 0)

// B=4, T=4096, E=1024, H=64
static constexpr float LOG2E = 1.44269504088896340736f;
static constexpr float QSCALE = LOG2E / 32.0f;  // E^-0.5 * log2(e), folded into q

// ws layout (bytes):
//   qs  [16384][64] bf16 @ 0     (2 MB)   q * QSCALE
//   ks  [16384][64] bf16 @ 2 MB  (2 MB)
//   vt  [4][64][4096] bf16 @ 4 MB (2 MB)  v transposed per batch
//   wt  [192][1024] bf16 @ 6 MB (384 KB)  (= [3][64][1024])
//   po  [1024][64][64] bf16 @ 8 MB (8 MB)
//   pm  [1024][64] f32 @ 16 MB (256 KB)
//   pls [1024][64] f32 @ 16.25 MB (256 KB)

__device__ __forceinline__ void gload_lds16(const bf16_t* src, bf16_t* dst) {
    __builtin_amdgcn_global_load_lds(
        (const __attribute__((address_space(1))) void*)src,
        (__attribute__((address_space(3))) void*)dst, 16, 0, 0);
}

// ---- DPP 16-lane-row reduces ----
template <int CTRL>
__device__ __forceinline__ float dppf(float v) {
    return __builtin_bit_cast(
        float, __builtin_amdgcn_mov_dpp(__builtin_bit_cast(int, v), CTRL, 0xf, 0xf, true));
}
__device__ __forceinline__ float rmax16(float t) {
    t = fmaxf(t, dppf<0xB1>(t));
    t = fmaxf(t, dppf<0x4E>(t));
    t = fmaxf(t, dppf<0x141>(t));
    t = fmaxf(t, dppf<0x140>(t));
    return t;
}
__device__ __forceinline__ float rsum16(float t) {
    t += dppf<0xB1>(t);
    t += dppf<0x4E>(t);
    t += dppf<0x141>(t);
    t += dppf<0x140>(t);
    return t;
}

// 48 blocks x 256: LDS tile transpose, coalesced both sides.
__global__ __launch_bounds__(256) void transpose_w_kernel(const float* __restrict__ Wq,
                                                          const float* __restrict__ Wk,
                                                          const float* __restrict__ Wv,
                                                          bf16_t* __restrict__ wt) {
    __shared__ float tile[64][68];
    int w = blockIdx.x >> 4;
    int e0 = (blockIdx.x & 15) * 64;
    const float* W = (w == 0) ? Wq : ((w == 1) ? Wk : Wv);
    int t = threadIdx.x;
    int r = t >> 2, q = t & 3;
    const float* src = W + (size_t)(e0 + r) * 64 + q * 16;
#pragma unroll
    for (int jj = 0; jj < 4; ++jj) {
        float4 v = *(const float4*)(src + jj * 4);
        *(float4*)&tile[r][q * 16 + jj * 4] = v;
    }
    __syncthreads();
    bf16_t* dst = wt + (size_t)w * 65536 + (size_t)r * 1024 + e0 + q * 16;
    bf16x8 o0, o1;
#pragma unroll
    for (int jj = 0; jj < 8; ++jj) o0[jj] = (bf16_t)tile[q * 16 + jj][r];
#pragma unroll
    for (int jj = 0; jj < 8; ++jj) o1[jj] = (bf16_t)tile[q * 16 + 8 + jj][r];
    *(bf16x8*)dst = o0;
    *(bf16x8*)(dst + 8) = o1;
}

// 1024 blocks x 256 (4 waves). Block: 32 rows x 96 cols (col-half = bid&1).
// K-chunks of 64 (16 chunks), LDS double-buffered (37 KB -> 4 blocks/CU):
// wt via global_load_lds (pre-swizzled source, linear dest); x reg-staged
// (distance-2 prefetch) f32->bf16, swizzled ds_write.
// Swizzle: 16B-unit e' = e ^ (row_or_col & 7) -> 2-way bank conflict (free).
__global__ __launch_bounds__(256) void proj_kernel(const float* __restrict__ x,
                                                   const bf16_t* __restrict__ wt,
                                                   bf16_t* __restrict__ qs,
                                                   bf16_t* __restrict__ ks,
                                                   bf16_t* __restrict__ vt) {
    __shared__ __align__(16) bf16_t xa[2][32 * 64];
    __shared__ __align__(16) bf16_t wb[2][96 * 64];
    __shared__ __align__(16) bf16_t vredb[64][40];

    int tid = threadIdx.x;
    int wave = tid >> 6, lane = tid & 63;
    int lr = lane & 15, lg = lane >> 4;
    int wr = wave >> 1, wc = wave & 1;
    int bid = blockIdx.x;
    int h2 = bid & 1;
    int r0 = (bid >> 1) << 5;

    const bf16_t* wtb = wt + (size_t)h2 * 96 * 1024;
    int wubase = tid & ~63;  // wave-uniform unit base for gload_lds dst

    // x staging geometry: thread -> (row = tid>>3, ep = tid&7), 8 f32 each
    int xrow = tid >> 3, xep = tid & 7;
    const float* xsrc = x + (size_t)(r0 + xrow) * 1024 + xep * 8;
    bf16_t* xdst0 = &xa[0][(size_t)(xrow * 8 + (xep ^ (xrow & 7))) * 8];
    bf16_t* xdst1 = &xa[1][(size_t)(xrow * 8 + (xep ^ (xrow & 7))) * 8];

    f32x4 acc[3];
#pragma unroll
    for (int cc = 0; cc < 3; ++cc) acc[cc] = (f32x4){0.f, 0.f, 0.f, 0.f};

    // ---- prologue ----
#pragma unroll
    for (int call = 0; call < 3; ++call) {
        int u = call * 256 + tid;
        int col = u >> 3, ep = u & 7;
        gload_lds16(wtb + (size_t)col * 1024 + ((ep ^ (col & 7)) * 8),
                    &wb[0][(size_t)(call * 256 + wubase) * 8]);
    }
    {
        float4 ca = *(const float4*)(xsrc);
        float4 cb = *(const float4*)(xsrc + 4);
        bf16x8 w0;
        w0[0] = (bf16_t)ca.x; w0[1] = (bf16_t)ca.y; w0[2] = (bf16_t)ca.z; w0[3] = (bf16_t)ca.w;
        w0[4] = (bf16_t)cb.x; w0[5] = (bf16_t)cb.y; w0[6] = (bf16_t)cb.z; w0[7] = (bf16_t)cb.w;
        *(bf16x8*)xdst0 = w0;
    }
    float4 fa0 = *(const float4*)(xsrc + 64), fa1 = *(const float4*)(xsrc + 68);    // chunk 1
    float4 fb0 = *(const float4*)(xsrc + 128), fb1 = *(const float4*)(xsrc + 132);  // chunk 2
    __syncthreads();

    for (int c = 0; c < 16; ++c) {
        int cur = c & 1;
        if (c < 15) {
            int k0 = (c + 1) * 64;
#pragma unroll
            for (int call = 0; call < 3; ++call) {
                int u = call * 256 + tid;
                int col = u >> 3, ep = u & 7;
                gload_lds16(wtb + (size_t)col * 1024 + k0 + ((ep ^ (col & 7)) * 8),
                            &wb[cur ^ 1][(size_t)(call * 256 + wubase) * 8]);
            }
        }

        // compute chunk c
        int arow = wr * 16 + lr;
#pragma unroll
        for (int ksi = 0; ksi < 2; ++ksi) {
            bf16x8 af = *(const bf16x8*)&xa[cur][(size_t)(arow * 8 + ((ksi * 4 + lg) ^ (arow & 7))) * 8];
#pragma unroll
            for (int cc = 0; cc < 3; ++cc) {
                int bcol = wc * 48 + cc * 16 + lr;
                bf16x8 bf = *(const bf16x8*)&wb[cur][(size_t)(bcol * 8 + ((ksi * 4 + lg) ^ (bcol & 7))) * 8];
                acc[cc] = MFMA16(af, bf, acc[cc]);
            }
        }

        if (c < 15) {
            // cvt+write chunk c+1's x (loaded 2 chunks ago -> no stall)
            bf16x8 w0;
            w0[0] = (bf16_t)fa0.x; w0[1] = (bf16_t)fa0.y; w0[2] = (bf16_t)fa0.z; w0[3] = (bf16_t)fa0.w;
            w0[4] = (bf16_t)fa1.x; w0[5] = (bf16_t)fa1.y; w0[6] = (bf16_t)fa1.z; w0[7] = (bf16_t)fa1.w;
            *(bf16x8*)((cur ^ 1) ? xdst1 : xdst0) = w0;
            fa0 = fb0; fa1 = fb1;
            if (c + 3 < 16) {
                fb0 = *(const float4*)(xsrc + (c + 3) * 64);
                fb1 = *(const float4*)(xsrc + (c + 3) * 64 + 4);
            }
        }
        __syncthreads();
    }

    // ---- epilogue: q/k direct, v via LDS transpose ----
#pragma unroll
    for (int cc = 0; cc < 3; ++cc) {
        int gcol = h2 * 96 + wc * 48 + cc * 16 + lr;
        int w3 = gcol >> 6, h = gcol & 63;
#pragma unroll
        for (int r = 0; r < 4; ++r) {
            int lrow = wr * 16 + lg * 4 + r;
            int row = r0 + lrow;
            float v = acc[cc][r];
            if (w3 == 0) {
                qs[(size_t)row * 64 + h] = (bf16_t)(v * QSCALE);
            } else if (w3 == 1) {
                ks[(size_t)row * 64 + h] = (bf16_t)v;
            } else {
                vredb[gcol & 63][lrow] = (bf16_t)v;
            }
        }
    }
    if (h2 == 1) {
        __syncthreads();
        int h = tid >> 2, j8 = (tid & 3) * 8;
        int bb = r0 >> 12, t0 = r0 & 4095;
        bf16x8 v8 = *(const bf16x8*)&vredb[h][j8];
        *(bf16x8*)(vt + ((size_t)(bb * 64 + h)) * 4096 + t0 + j8) = v8;
    }
}

// 1024 blocks x 256 (4 waves): {b:4} x {qt:64 of QBLK=64 rows} x {split:4}.
// Wave w owns rows q0+16w..+16. K/V tiles (64 keys) cooperatively staged in
// LDS, double-buffered, reg-prefetch before compute. T13 defer-max softmax.
__global__ __launch_bounds__(256) void attn_kernel(const bf16_t* __restrict__ qs,
                                                   const bf16_t* __restrict__ ks,
                                                   const bf16_t* __restrict__ vt,
                                                   bf16_t* __restrict__ po,
                                                   float* __restrict__ pm,
                                                   float* __restrict__ pls) {
    __shared__ __align__(16) bf16_t kt[2][64 * 64];
    __shared__ __align__(16) bf16_t vtl[2][64 * 64];
    __shared__ __align__(16) bf16_t pl[4][16][80];

    int tid = threadIdx.x;
    int wave = tid >> 6, lane = tid & 63;
    int lr = lane & 15, lg = lane >> 4;

    int bid = blockIdx.x;
    int s = bid & 3;
    int jq = (bid >> 2) & 63;
    int b = bid >> 8;
    int qt = (jq & 1) ? (63 - (jq >> 1)) : (jq >> 1);  // triangle balance
    int q0 = qt << 6;
    int nk = qt + 1;
    int lo = (nk * s) >> 2;
    int hi = (nk * (s + 1)) >> 2;
    int ntile = hi - lo;

    int srow = tid >> 3, sc = tid & 7;
    int sw8 = srow & 7;
    int koff0 = srow * 64 + ((sc ^ sw8) * 8);
    int koff1 = (32 + srow) * 64 + ((sc ^ sw8) * 8);
    const bf16_t* kg = ks + ((size_t)b * 4096) * 64;
    const bf16_t* vg = vt + ((size_t)b * 64) * 4096;

    const bf16_t* qb = qs + (size_t)(b * 4096 + q0 + wave * 16 + lr) * 64 + lg * 8;
    bf16x8 qf0 = *(const bf16x8*)qb;
    bf16x8 qf1 = *(const bf16x8*)(qb + 32);

    f32x4 o[4];
    float m[4], l[4];
#pragma unroll
    for (int r = 0; r < 4; ++r) {
        o[r] = (f32x4){0.f, 0.f, 0.f, 0.f};
        m[r] = -INFINITY;
        l[r] = 0.f;
    }

    bf16x8 kr0, kr1, vr0, vr1;
    if (ntile > 0) {
        int kb = lo << 6;
        kr0 = *(const bf16x8*)(kg + (size_t)(kb + srow) * 64 + sc * 8);
        kr1 = *(const bf16x8*)(kg + (size_t)(kb + 32 + srow) * 64 + sc * 8);
        vr0 = *(const bf16x8*)(vg + (size_t)srow * 4096 + kb + sc * 8);
        vr1 = *(const bf16x8*)(vg + (size_t)(32 + srow) * 4096 + kb + sc * 8);
    }

    for (int ti = 0; ti < ntile; ++ti) {
        int cur = ti & 1;
        *(bf16x8*)(&kt[cur][koff0]) = kr0;
        *(bf16x8*)(&kt[cur][koff1]) = kr1;
        *(bf16x8*)(&vtl[cur][koff0]) = vr0;
        *(bf16x8*)(&vtl[cur][koff1]) = vr1;
        __syncthreads();
        if (ti + 1 < ntile) {
            int kb = (lo + ti + 1) << 6;
            kr0 = *(const bf16x8*)(kg + (size_t)(kb + srow) * 64 + sc * 8);
            kr1 = *(const bf16x8*)(kg + (size_t)(kb + 32 + srow) * 64 + sc * 8);
            vr0 = *(const bf16x8*)(vg + (size_t)srow * 4096 + kb + sc * 8);
            vr1 = *(const bf16x8*)(vg + (size_t)(32 + srow) * 4096 + kb + sc * 8);
        }

        int gt = lo + ti;
        int kb = gt << 6;
        const bf16_t* kbuf = kt[cur];
        const bf16_t* vbuf = vtl[cur];

        f32x4 z = {0.f, 0.f, 0.f, 0.f};
        f32x4 sv[4];
#pragma unroll
        for (int g = 0; g < 4; ++g) {
            int krow = g * 16 + lr;
            int sw = krow & 7;
            bf16x8 kf0 = *(const bf16x8*)(kbuf + krow * 64 + ((lg ^ sw) * 8));
            bf16x8 kf1 = *(const bf16x8*)(kbuf + krow * 64 + (((4 | lg) ^ sw) * 8));
            sv[g] = MFMA16(qf0, kf0, z);
            sv[g] = MFMA16(qf1, kf1, sv[g]);
        }

        if (gt == nk - 1) {
#pragma unroll
            for (int r = 0; r < 4; ++r) {
                int qrow = q0 + wave * 16 + lg * 4 + r;
#pragma unroll
                for (int g = 0; g < 4; ++g)
                    if (kb + g * 16 + lr > qrow) sv[g][r] = -INFINITY;
            }
        }

        // T13 defer-max: only rescale when some row's max grew by > 8 (log2)
        float t2v[4];
#pragma unroll
        for (int r = 0; r < 4; ++r) {
            float t2 = fmaxf(fmaxf(sv[0][r], sv[1][r]), fmaxf(sv[2][r], sv[3][r]));
            t2v[r] = rmax16(t2);
        }
        float grow = fmaxf(fmaxf(t2v[0] - m[0], t2v[1] - m[1]),
                           fmaxf(t2v[2] - m[2], t2v[3] - m[3]));
        if (!__all(grow <= 8.0f)) {
#pragma unroll
            for (int r = 0; r < 4; ++r) {
                float mn = fmaxf(m[r], t2v[r]);
                float a = __builtin_amdgcn_exp2f(m[r] - mn);
                l[r] *= a;
                o[0][r] *= a; o[1][r] *= a; o[2][r] *= a; o[3][r] *= a;
                m[r] = mn;
            }
        }
#pragma unroll
        for (int r = 0; r < 4; ++r) {
            float p0 = __builtin_amdgcn_exp2f(sv[0][r] - m[r]);
            float p1 = __builtin_amdgcn_exp2f(sv[1][r] - m[r]);
            float p2 = __builtin_amdgcn_exp2f(sv[2][r] - m[r]);
            float p3 = __builtin_amdgcn_exp2f(sv[3][r] - m[r]);
            float rs = rsum16((p0 + p1) + (p2 + p3));
            l[r] += rs;
            int prow = lg * 4 + r;
            pl[wave][prow][lr] = (bf16_t)p0;
            pl[wave][prow][16 + lr] = (bf16_t)p1;
            pl[wave][prow][32 + lr] = (bf16_t)p2;
            pl[wave][prow][48 + lr] = (bf16_t)p3;
        }

        bf16x8 pa0 = *(const bf16x8*)&pl[wave][lr][lg * 8];
        bf16x8 pa1 = *(const bf16x8*)&pl[wave][lr][32 + lg * 8];
#pragma unroll
        for (int oc = 0; oc < 4; ++oc) {
            int drow = oc * 16 + lr;
            int sw = drow & 7;
            bf16x8 vf0 = *(const bf16x8*)(vbuf + drow * 64 + ((lg ^ sw) * 8));
            bf16x8 vf1 = *(const bf16x8*)(vbuf + drow * 64 + (((4 | lg) ^ sw) * 8));
            o[oc] = MFMA16(pa0, vf0, o[oc]);
            o[oc] = MFMA16(pa1, vf1, o[oc]);
        }
    }

    size_t pblk = ((size_t)((b << 6) + qt) << 2) + s;
    bf16_t* pop = po + pblk * 4096;
#pragma unroll
    for (int r = 0; r < 4; ++r) {
        int row = wave * 16 + lg * 4 + r;
#pragma unroll
        for (int oc = 0; oc < 4; ++oc) pop[row * 64 + oc * 16 + lr] = (bf16_t)o[oc][r];
        if (lr == r) {
            pm[pblk * 64 + row] = m[r];
            pls[pblk * 64 + row] = l[r];
        }
    }
}

// 256 blocks x 256: merge the 4 key-splits per row, normalize, write f32 out.
__global__ __launch_bounds__(256) void merge_kernel(const bf16_t* __restrict__ po,
                                                    const float* __restrict__ pm,
                                                    const float* __restrict__ pls,
                                                    float* __restrict__ out) {
    int gid = blockIdx.x * 256 + threadIdx.x;
    int row = gid >> 2, cq = gid & 3;
    int b = row >> 12, t = row & 4095;
    int qt = t >> 6, lrow = t & 63;
    int pb = ((b << 6) + qt) << 2;

    float mm[4], w[4];
    float M = -INFINITY;
#pragma unroll
    for (int i = 0; i < 4; ++i) {
        mm[i] = pm[(size_t)(pb + i) * 64 + lrow];
        M = fmaxf(M, mm[i]);
    }
    float L = 0.f;
#pragma unroll
    for (int i = 0; i < 4; ++i) {
        w[i] = (mm[i] == -INFINITY) ? 0.f : __builtin_amdgcn_exp2f(mm[i] - M);
        L += pls[(size_t)(pb + i) * 64 + lrow] * w[i];
    }
    float rL = 1.0f / L;

    float acc[16];
#pragma unroll
    for (int j = 0; j < 16; ++j) acc[j] = 0.f;
#pragma unroll
    for (int i = 0; i < 4; ++i) {
        const bf16_t* p = po + ((size_t)(pb + i) * 64 + lrow) * 64 + cq * 16;
        bf16x8 x0 = *(const bf16x8*)p, x1 = *(const bf16x8*)(p + 8);
#pragma unroll
        for (int j = 0; j < 8; ++j) acc[j] += w[i] * (float)x0[j];
#pragma unroll
        for (int j = 0; j < 8; ++j) acc[8 + j] += w[i] * (float)x1[j];
    }
    float* op = out + (size_t)row * 64 + cq * 16;
#pragma unroll
    for (int j = 0; j < 16; ++j) op[j] = acc[j] * rL;
}

extern "C" void kernel_launch(void* const* d_in, const int* in_sizes, int n_in,
                              void* d_out, int out_size, void* d_ws, size_t ws_size,
                              hipStream_t stream) {
    const float* x  = (const float*)d_in[0];
    const float* Wq = (const float*)d_in[1];
    const float* Wk = (const float*)d_in[2];
    const float* Wv = (const float*)d_in[3];
    float* out = (float*)d_out;

    char* ws = (char*)d_ws;
    bf16_t* qs = (bf16_t*)(ws);
    bf16_t* ks = (bf16_t*)(ws + (2u << 20));
    bf16_t* vt = (bf16_t*)(ws + (4u << 20));
    bf16_t* wt = (bf16_t*)(ws + (6u << 20));
    bf16_t* po = (bf16_t*)(ws + (8u << 20));
    float*  pm = (float*)(ws + (16u << 20));
    float*  pls = (float*)(ws + (16u << 20) + (256u << 10));

    transpose_w_kernel<<<48, 256, 0, stream>>>(Wq, Wk, Wv, wt);
    proj_kernel<<<1024, 256, 0, stream>>>(x, wt, qs, ks, vt);
    attn_kernel<<<1024, 256, 0, stream>>>(qs, ks, vt, po, pm, pls);
    merge_kernel<<<256, 256, 0, stream>>>(po, pm, pls, out);
}